// Round 19
// baseline (489.573 us; speedup 1.0000x reference)
//
#include <hip/hip_runtime.h>
#include <hip/hip_bf16.h>
#include <cstdint>

#define IN_C 256

typedef __attribute__((ext_vector_type(8))) short bf16x8;
typedef __attribute__((ext_vector_type(8))) short s16x8;
typedef __attribute__((ext_vector_type(8))) unsigned short u16x8;
typedef __attribute__((ext_vector_type(4))) float f32x4;

#define FIXED_SCALE 33554432.0f          // 2^25
#define FIXED_INV   (1.0f / 33554432.0f)
#define DEG_MASK    ((1ULL << 40) - 1)

// ---- bf16 helpers (RNE) ----
__device__ inline unsigned short f2bf(float f) {
    union { float f; unsigned int u; } v; v.f = f;
    unsigned int r = (v.u + 0x7fffu + ((v.u >> 16) & 1u)) >> 16;
    return (unsigned short)r;
}
__device__ inline float bf2f(unsigned short b) {
    union { unsigned int u; float f; } v; v.u = ((unsigned int)b) << 16;
    return v.f;
}
// returns .x = hi bf16 bits, .y = lo bf16 bits
__device__ inline short2 split1(float f) {
    unsigned short hb = f2bf(f);
    unsigned short lb = f2bf(f - bf2f(hb));
    return make_short2((short)hb, (short)lb);
}

// ---------------- build1: deg_count  ||  W prep  ||  x->bf16 convert ----------------
// All three independent; fused so prep/convert blocks back-fill CUs while the
// atomic-bound deg_count blocks (VALUBusy 0.3%, HBM 9%) wait on L2 atomics.
// Blocks [0,nbE): per-edge packed u64 atomic = deg(fixed-point)+cnt; returns rank.
// Blocks [nbE,nbE+512): W1/W2 transpose + hi/lo split (b<nbE+256 -> W1).
// Blocks [nbE+512,...): x plain-bf16 convert, 8 floats/thread.
__global__ void build1_kernel(const int* __restrict__ ei, const float* __restrict__ w,
                              unsigned long long* __restrict__ packed,
                              unsigned short* __restrict__ rank, int E, int nbE,
                              const float* __restrict__ W1, const float* __restrict__ W2,
                              unsigned short* __restrict__ w1t_hi, unsigned short* __restrict__ w1t_lo,
                              unsigned short* __restrict__ w2t_hi, unsigned short* __restrict__ w2t_lo,
                              const float* __restrict__ x, unsigned short* __restrict__ x16,
                              int nx8) {
    int b = blockIdx.x;
    if (b < nbE) {
        int e = b * 256 + threadIdx.x;
        if (e < E) {
            int dst = ei[E + e];
            unsigned int fx = __float2uint_rn(w[e] * FIXED_SCALE);
            unsigned long long inc = (1ULL << 40) | (unsigned long long)fx;
            unsigned long long old = atomicAdd(&packed[dst], inc);
            rank[e] = (unsigned short)(old >> 40);
        }
    } else if (b < nbE + 512) {
        int bb = b - nbE;
        const float* W = (bb < 256) ? W1 : W2;
        unsigned short* hi = (bb < 256) ? w1t_hi : w2t_hi;
        unsigned short* lo = (bb < 256) ? w1t_lo : w2t_lo;
        int n = bb & 255;      // col of W
        int k = threadIdx.x;   // row of W
        float v = W[(size_t)k * 256 + n];
        short2 s = split1(v);
        hi[(size_t)n * 256 + k] = (unsigned short)s.x;
        lo[(size_t)n * 256 + k] = (unsigned short)s.y;
    } else {
        int i = (b - nbE - 512) * 256 + threadIdx.x;   // 8-float group index
        if (i < nx8) {
            const float4* xp = (const float4*)x + 2 * (size_t)i;
            float4 v0 = xp[0], v1 = xp[1];
            u16x8 o;
            o[0] = f2bf(v0.x); o[1] = f2bf(v0.y); o[2] = f2bf(v0.z); o[3] = f2bf(v0.w);
            o[4] = f2bf(v1.x); o[5] = f2bf(v1.y); o[6] = f2bf(v1.z); o[7] = f2bf(v1.w);
            *(u16x8*)(x16 + (size_t)i * 8) = o;
        }
    }
}

// ---------------- exclusive scan of cnt -> row_ptr (3-kernel); scan1 also dinv ----------------
#define SCAN_B 256
__global__ void scan1_kernel(const unsigned long long* __restrict__ packed,
                             int* __restrict__ rp, int* __restrict__ bsum,
                             float* __restrict__ dinv, int N) {
    __shared__ int s[SCAN_B];
    int tid = threadIdx.x;
    int i = blockIdx.x * SCAN_B + tid;
    int v = 0;
    if (i < N) {
        unsigned long long pk = packed[i];
        v = (int)(pk >> 40);
        float deg = (float)(pk & DEG_MASK) * FIXED_INV;
        dinv[i] = rsqrtf(deg + 1.0f);         // +1 = self loop weight
    }
    s[tid] = v;
    __syncthreads();
    for (int off = 1; off < SCAN_B; off <<= 1) {
        int t = (tid >= off) ? s[tid - off] : 0;
        __syncthreads();
        s[tid] += t;
        __syncthreads();
    }
    if (i < N) rp[i] = s[tid] - v;            // exclusive within block
    if (tid == SCAN_B - 1) bsum[blockIdx.x] = s[tid];
}

__global__ void scan2_kernel(int* __restrict__ bsum, int* __restrict__ boff, int nb) {
    __shared__ int s[SCAN_B];
    int tid = threadIdx.x;
    int v = (tid < nb) ? bsum[tid] : 0;
    s[tid] = v;
    __syncthreads();
    for (int off = 1; off < SCAN_B; off <<= 1) {
        int t = (tid >= off) ? s[tid - off] : 0;
        __syncthreads();
        s[tid] += t;
        __syncthreads();
    }
    if (tid < nb) boff[tid] = s[tid] - v;     // exclusive across blocks
}

__global__ void scan3_kernel(int* __restrict__ rp, const int* __restrict__ boff,
                             int N, int E) {
    int i = blockIdx.x * blockDim.x + threadIdx.x;
    if (i < N) rp[i] = rp[i] + boff[i >> 8];
    if (i == 0) rp[N] = E;
}

// ---------------- GEMM body (device fn): C16 = A16 @ (Bh+Bl), plain-A 2-MFMA ----------------
// C16[N][256] plain bf16 out; A plain bf16 (its bf16 rounding == dropped al*bh
// term of the 3-MFMA split ladder — proven in R17); B hi/lo split.
__device__ inline void gemm_body(const unsigned short* __restrict__ A16,
                                 const unsigned short* __restrict__ Bth,
                                 const unsigned short* __restrict__ Btl,
                                 unsigned short* __restrict__ C16, int Nrows,
                                 int bx, int by) {
    __shared__ __align__(16) short Ah[128 * 64];
    __shared__ __align__(16) short Bh[128 * 64];
    __shared__ __align__(16) short Bl[128 * 64];

    const int t    = threadIdx.x;
    const int lane = t & 63;
    const int w    = t >> 6;
    const int r0   = bx * 128;
    const int cb0  = by * 128;
    const int fr   = lane & 15;          // frag row (A: m-row / B: n-col)
    const int fk   = (lane >> 4) * 8;    // frag k offset
    const int wm   = w * 32;             // wave's m-band

    f32x4 acc[2][8] = {};

    for (int k0 = 0; k0 < 256; k0 += 64) {
        __syncthreads();
        // ---- stage B tile [128 n][64 k] (hi+lo) ----
#pragma unroll
        for (int c = 0; c < 4; ++c) {
            int i = c * 256 + t;
            int row = i >> 3, seg = i & 7;
            size_t g = (size_t)(cb0 + row) * 256 + k0 + seg * 8;
            *(s16x8*)&Bh[row * 64 + seg * 8] = *(const s16x8*)(Bth + g);
            *(s16x8*)&Bl[row * 64 + seg * 8] = *(const s16x8*)(Btl + g);
        }
        // ---- stage A tile [128 m][64 k] ----
#pragma unroll
        for (int c = 0; c < 4; ++c) {
            int i = c * 256 + t;
            int row = i >> 3, seg = i & 7;
            int gr = r0 + row; if (gr > Nrows - 1) gr = Nrows - 1;
            size_t g = (size_t)gr * 256 + k0 + seg * 8;
            *(s16x8*)&Ah[row * 64 + seg * 8] = *(const s16x8*)(A16 + g);
        }
        __syncthreads();
        // ---- compute: 2 k-steps of 32, 2m x 8n frags, 2 MFMA each ----
#pragma unroll
        for (int ks = 0; ks < 2; ++ks) {
            int ko = ks * 32 + fk;
            bf16x8 ah[2];
#pragma unroll
            for (int mi = 0; mi < 2; ++mi)
                ah[mi] = *(const bf16x8*)&Ah[(wm + mi * 16 + fr) * 64 + ko];
#pragma unroll
            for (int n = 0; n < 8; ++n) {
                bf16x8 bh = *(const bf16x8*)&Bh[(n * 16 + fr) * 64 + ko];
                bf16x8 bl = *(const bf16x8*)&Bl[(n * 16 + fr) * 64 + ko];
#pragma unroll
                for (int mi = 0; mi < 2; ++mi) {
                    acc[mi][n] = __builtin_amdgcn_mfma_f32_16x16x32_bf16(ah[mi], bh, acc[mi][n], 0, 0, 0);
                    acc[mi][n] = __builtin_amdgcn_mfma_f32_16x16x32_bf16(ah[mi], bl, acc[mi][n], 0, 0, 0);
                }
            }
        }
    }
    // ---- epilogue: C/D layout col=lane&15, row=(lane>>4)*4+reg; store plain bf16 ----
    const int rb = (lane >> 4) * 4;
#pragma unroll
    for (int mi = 0; mi < 2; ++mi) {
#pragma unroll
        for (int n = 0; n < 8; ++n) {
            int col = cb0 + n * 16 + fr;
#pragma unroll
            for (int r = 0; r < 4; ++r) {
                int row = r0 + wm + mi * 16 + rb + r;
                if (row < Nrows) C16[(size_t)row * 256 + col] = f2bf(acc[mi][n][r]);
            }
        }
    }
}

// ---------------- build2: CSR fill (atomic-free)  ||  GEMM1 ----------------
// fill needs scan3's rp; GEMM1 needs build1's x16/W — both ready. Fusing
// overlaps fill's scatter-store latency with GEMM1's MFMA compute.
__global__ __launch_bounds__(256) void build2_kernel(
    const int* __restrict__ ei, const float* __restrict__ w,
    const float* __restrict__ dinv, const int* __restrict__ rp,
    const unsigned short* __restrict__ rank, int2* __restrict__ cv,
    int E, int nbE,
    const unsigned short* __restrict__ A16,
    const unsigned short* __restrict__ Bth, const unsigned short* __restrict__ Btl,
    unsigned short* __restrict__ C16, int Nrows) {
    int b = blockIdx.x;
    if (b < nbE) {
        int e = b * 256 + threadIdx.x;
        if (e < E) {
            int src = ei[e];
            int dst = ei[E + e];
            int pos = rp[dst] + (int)rank[e];
            // defensive clamp: never allow a wild store outside [0,E)
            if ((unsigned)pos < (unsigned)E) {
                float v = dinv[src] * w[e] * dinv[dst];
                cv[pos] = make_int2(src, __float_as_int(v));
            }
        }
    } else {
        int g = b - nbE;
        gemm_body(A16, Bth, Btl, C16, Nrows, g >> 1, g & 1);
    }
}

// ---------------- GEMM2 standalone ----------------
__global__ __launch_bounds__(256) void gemm_kernel(
    const unsigned short* __restrict__ A16,
    const unsigned short* __restrict__ Bth, const unsigned short* __restrict__ Btl,
    unsigned short* __restrict__ C16, int Nrows) {
    gemm_body(A16, Bth, Btl, C16, Nrows, blockIdx.x, blockIdx.y);
}

// ---- 8-channel bf16 FMA helper ----
__device__ inline void fma8(float* acc, u16x8 g, float v) {
#pragma unroll
    for (int c = 0; c < 8; ++c) acc[c] = fmaf(v, bf2f(g[c]), acc[c]);
}

// ---------------- CSR aggregation + self loop + bias + relu (+optional fused head) ----
// R13-proven structure (112us, FETCH 361MB): bf16-h gather, HALF-WAVE-per-edge
// keeps the 16B/lane global_load_dwordx4 shape (8B loads collapse to ~2 in
// flight, 6.7x slower — R6/R7). One wave per dst; lane l handles 8 channels
// [8*(l&31),+8) of edge j+2t+(l>>5); 16-edge main loop = 8 dwordx4 in flight,
// 8-edge mid tier, then 2/1-edge tail. cv = packed (col,val).
// Channel-phasing REFUTED (R14/R15) — full-row gathers use every fetched byte.
// MODE 0: relu + plain bf16 out (half0 stores; lo-drop proven free in R17).
// MODE 1: relu + fused head (wave-reduce).
template<int MODE>
__global__ __launch_bounds__(256) void agg_kernel(const unsigned short* __restrict__ h16,
                                                  const int* __restrict__ rp,
                                                  const int2* __restrict__ cv,
                                                  const float* __restrict__ dinv,
                                                  const float* __restrict__ bias,
                                                  unsigned short* __restrict__ out_hi,
                                                  const float* __restrict__ Wf,
                                                  const float* __restrict__ bf,
                                                  float* __restrict__ out,
                                                  int N) {
    int d    = blockIdx.x * 4 + (threadIdx.x >> 6);
    int lane = threadIdx.x & 63;
    if (d >= N) return;
    int half = lane >> 5;
    int co   = (lane & 31) * 8;          // this lane's channel offset

    float di = dinv[d];
    float selfm = half ? 0.0f : di * di;           // count self loop once
    u16x8 sv = *(const u16x8*)(h16 + (size_t)d * 256 + co);
    float acc[8];
#pragma unroll
    for (int c = 0; c < 8; ++c) acc[c] = selfm * bf2f(sv[c]);

    int s = rp[d], e = rp[d + 1];
    int j = s;
    for (; j + 16 <= e; j += 16) {
        int   ec[8]; float ev[8];
#pragma unroll
        for (int t2 = 0; t2 < 8; ++t2) {
            int2 ca = cv[j + 2 * t2], cb = cv[j + 2 * t2 + 1];
            ec[t2] = half ? cb.x : ca.x;
            ev[t2] = __int_as_float(half ? cb.y : ca.y);
        }
        u16x8 g0 = *(const u16x8*)(h16 + (size_t)ec[0] * 256 + co);
        u16x8 g1 = *(const u16x8*)(h16 + (size_t)ec[1] * 256 + co);
        u16x8 g2 = *(const u16x8*)(h16 + (size_t)ec[2] * 256 + co);
        u16x8 g3 = *(const u16x8*)(h16 + (size_t)ec[3] * 256 + co);
        u16x8 g4 = *(const u16x8*)(h16 + (size_t)ec[4] * 256 + co);
        u16x8 g5 = *(const u16x8*)(h16 + (size_t)ec[5] * 256 + co);
        u16x8 g6 = *(const u16x8*)(h16 + (size_t)ec[6] * 256 + co);
        u16x8 g7 = *(const u16x8*)(h16 + (size_t)ec[7] * 256 + co);
        fma8(acc, g0, ev[0]);
        fma8(acc, g1, ev[1]);
        fma8(acc, g2, ev[2]);
        fma8(acc, g3, ev[3]);
        fma8(acc, g4, ev[4]);
        fma8(acc, g5, ev[5]);
        fma8(acc, g6, ev[6]);
        fma8(acc, g7, ev[7]);
    }
    for (; j + 8 <= e; j += 8) {
        int   ec[4]; float ev[4];
#pragma unroll
        for (int t2 = 0; t2 < 4; ++t2) {
            int2 ca = cv[j + 2 * t2], cb = cv[j + 2 * t2 + 1];
            ec[t2] = half ? cb.x : ca.x;
            ev[t2] = __int_as_float(half ? cb.y : ca.y);
        }
        u16x8 g0 = *(const u16x8*)(h16 + (size_t)ec[0] * 256 + co);
        u16x8 g1 = *(const u16x8*)(h16 + (size_t)ec[1] * 256 + co);
        u16x8 g2 = *(const u16x8*)(h16 + (size_t)ec[2] * 256 + co);
        u16x8 g3 = *(const u16x8*)(h16 + (size_t)ec[3] * 256 + co);
        fma8(acc, g0, ev[0]);
        fma8(acc, g1, ev[1]);
        fma8(acc, g2, ev[2]);
        fma8(acc, g3, ev[3]);
    }
    for (; j + 2 <= e; j += 2) {
        int2 ca = cv[j], cb = cv[j + 1];
        int   ee = half ? cb.x : ca.x;
        float vv = __int_as_float(half ? cb.y : ca.y);
        u16x8 g = *(const u16x8*)(h16 + (size_t)ee * 256 + co);
        fma8(acc, g, vv);
    }
    if (j < e) {                                    // single leftover edge
        int2 ca = cv[j];
        int   ee = ca.x;
        float vv = half ? 0.0f : __int_as_float(ca.y);
        u16x8 g = *(const u16x8*)(h16 + (size_t)ee * 256 + co);
        fma8(acc, g, vv);
    }

    // combine halves: both halves end with the full per-channel sums
#pragma unroll
    for (int c = 0; c < 8; ++c) acc[c] += __shfl_xor(acc[c], 32);

    float4 b0 = *(const float4*)(bias + co);
    float4 b1 = *(const float4*)(bias + co + 4);
    acc[0] = fmaxf(acc[0] + b0.x, 0.0f);
    acc[1] = fmaxf(acc[1] + b0.y, 0.0f);
    acc[2] = fmaxf(acc[2] + b0.z, 0.0f);
    acc[3] = fmaxf(acc[3] + b0.w, 0.0f);
    acc[4] = fmaxf(acc[4] + b1.x, 0.0f);
    acc[5] = fmaxf(acc[5] + b1.y, 0.0f);
    acc[6] = fmaxf(acc[6] + b1.z, 0.0f);
    acc[7] = fmaxf(acc[7] + b1.w, 0.0f);

    if constexpr (MODE == 0) {
        if (half == 0) {
            u16x8 hi;
#pragma unroll
            for (int c = 0; c < 8; ++c) hi[c] = f2bf(acc[c]);
            *(u16x8*)(out_hi + (size_t)d * 256 + co) = hi;
        }
    } else {
        float4 wf0 = *(const float4*)(Wf + co);
        float4 wf1 = *(const float4*)(Wf + co + 4);
        float sdot = acc[0] * wf0.x + acc[1] * wf0.y + acc[2] * wf0.z + acc[3] * wf0.w
                   + acc[4] * wf1.x + acc[5] * wf1.y + acc[6] * wf1.z + acc[7] * wf1.w;
        for (int o = 16; o; o >>= 1) sdot += __shfl_down(sdot, o);   // per-half reduce
        if (lane == 0) out[d] = sdot + bf[0];
    }
}

// ---------------- host launch ----------------
extern "C" void kernel_launch(void* const* d_in, const int* in_sizes, int n_in,
                              void* d_out, int out_size, void* d_ws, size_t ws_size,
                              hipStream_t stream) {
    const float* x  = (const float*)d_in[0];
    const int*   ei = (const int*)d_in[1];
    const float* w  = (const float*)d_in[2];
    const float* W1 = (const float*)d_in[3];
    const float* b1 = (const float*)d_in[4];
    const float* W2 = (const float*)d_in[5];
    const float* b2 = (const float*)d_in[6];
    const float* Wf = (const float*)d_in[7];
    const float* bf = (const float*)d_in[8];
    float* out = (float*)d_out;

    const int N = in_sizes[0] / IN_C;
    const int E = in_sizes[2];

    // workspace layout (256B aligned)
    auto align256 = [](size_t v) { return (v + 255) & ~(size_t)255; };
    char* p = (char*)d_ws;
    unsigned long long* packed = (unsigned long long*)p; p += align256((size_t)N * 8);
    float* dinv   = (float*)p; p += align256((size_t)N * 4);
    int*   rp     = (int*)p;   p += align256(((size_t)N + 1) * 4);
    int*   bsum   = (int*)p;   p += align256(SCAN_B * 4);
    int*   boff   = (int*)p;   p += align256(SCAN_B * 4);
    unsigned short* rank = (unsigned short*)p; p += align256((size_t)E * 2);
    int2*  cv     = (int2*)p;  p += align256((size_t)E * 8);
    unsigned short* w1t_hi = (unsigned short*)p; p += align256((size_t)256 * 256 * 2);
    unsigned short* w1t_lo = (unsigned short*)p; p += align256((size_t)256 * 256 * 2);
    unsigned short* w2t_hi = (unsigned short*)p; p += align256((size_t)256 * 256 * 2);
    unsigned short* w2t_lo = (unsigned short*)p; p += align256((size_t)256 * 256 * 2);
    unsigned short* hbuf  = (unsigned short*)p; p += align256((size_t)N * 256 * 2);  // bf16 GEMM out
    // xa16: x plain bf16 (read by GEMM1), then REUSED as a1 (plain bf16) by agg1
    unsigned short* xa16 = (unsigned short*)p; p += align256((size_t)N * 256 * 2);
    (void)ws_size; (void)n_in; (void)out_size;

    const int nbE     = (E + 255) / 256;
    const int nb_nodes = (N + 255) / 256;
    const int nb_scan  = (N + SCAN_B - 1) / SCAN_B;
    const int nx8      = N * 256 / 8;
    const int nb_x     = (nx8 + 255) / 256;
    const int nb_gemm  = ((N + 127) / 128) * 2;

    // zero packed deg/cnt accumulators
    hipMemsetAsync(packed, 0, (size_t)N * 8, stream);

    // build1: deg_count || W prep || x convert
    build1_kernel<<<nbE + 512 + nb_x, 256, 0, stream>>>(
        ei, w, packed, rank, E, nbE,
        W1, W2, w1t_hi, w1t_lo, w2t_hi, w2t_lo, x, xa16, nx8);

    // scan chain
    scan1_kernel<<<nb_scan, SCAN_B, 0, stream>>>(packed, rp, bsum, dinv, N);
    scan2_kernel<<<1, SCAN_B, 0, stream>>>(bsum, boff, nb_scan);
    scan3_kernel<<<nb_nodes, 256, 0, stream>>>(rp, boff, N, E);

    // build2: fill || GEMM1 (h1 = x @ W1)
    build2_kernel<<<nbE + nb_gemm, 256, 0, stream>>>(
        ei, w, dinv, rp, rank, cv, E, nbE,
        xa16, w1t_hi, w1t_lo, hbuf, N);

    const int nb_agg = (N + 3) / 4;
    dim3 ggrid((N + 127) / 128, 2);

    // agg1 (plain bf16 a1 into xa16)
    agg_kernel<0><<<nb_agg, 256, 0, stream>>>(hbuf, rp, cv, dinv, b1,
                                              xa16, nullptr, nullptr, nullptr, N);
    // layer 2: GEMM (plain bf16 a1) -> bf16 h -> agg2 + fused head
    gemm_kernel<<<ggrid, 256, 0, stream>>>(xa16, w2t_hi, w2t_lo, hbuf, N);
    agg_kernel<1><<<nb_agg, 256, 0, stream>>>(hbuf, rp, cv, dinv, b2,
                                              nullptr, Wf, bf, out, N);
}

// Round 20
// 431.794 us; speedup vs baseline: 1.1338x; 1.1338x over previous
//
#include <hip/hip_runtime.h>
#include <hip/hip_bf16.h>
#include <cstdint>

#define IN_C 256

typedef __attribute__((ext_vector_type(8))) short bf16x8;
typedef __attribute__((ext_vector_type(8))) short s16x8;
typedef __attribute__((ext_vector_type(8))) unsigned short u16x8;
typedef __attribute__((ext_vector_type(4))) float f32x4;

#define FIXED_SCALE 33554432.0f          // 2^25
#define FIXED_INV   (1.0f / 33554432.0f)
#define DEG_MASK    ((1ULL << 40) - 1)

// ---- bf16 helpers (RNE) ----
__device__ inline unsigned short f2bf(float f) {
    union { float f; unsigned int u; } v; v.f = f;
    unsigned int r = (v.u + 0x7fffu + ((v.u >> 16) & 1u)) >> 16;
    return (unsigned short)r;
}
__device__ inline float bf2f(unsigned short b) {
    union { unsigned int u; float f; } v; v.u = ((unsigned int)b) << 16;
    return v.f;
}
// returns .x = hi bf16 bits, .y = lo bf16 bits
__device__ inline short2 split1(float f) {
    unsigned short hb = f2bf(f);
    unsigned short lb = f2bf(f - bf2f(hb));
    return make_short2((short)hb, (short)lb);
}

// ---------------- build1: deg_count  ||  W prep  ||  x->bf16 convert ----------------
// All three independent, all low-VGPR/no-LDS (resource footprints comparable —
// the R19 build2 fusion FAILED because fill blocks inherited the GEMM branch's
// 48KB LDS/148 VGPR and dropped to 10% occupancy; fuse only like with like).
__global__ void build1_kernel(const int* __restrict__ ei, const float* __restrict__ w,
                              unsigned long long* __restrict__ packed,
                              unsigned short* __restrict__ rank, int E, int nbE,
                              const float* __restrict__ W1, const float* __restrict__ W2,
                              unsigned short* __restrict__ w1t_hi, unsigned short* __restrict__ w1t_lo,
                              unsigned short* __restrict__ w2t_hi, unsigned short* __restrict__ w2t_lo,
                              const float* __restrict__ x, unsigned short* __restrict__ x16,
                              int nx8) {
    int b = blockIdx.x;
    if (b < nbE) {
        int e = b * 256 + threadIdx.x;
        if (e < E) {
            int dst = ei[E + e];
            unsigned int fx = __float2uint_rn(w[e] * FIXED_SCALE);
            unsigned long long inc = (1ULL << 40) | (unsigned long long)fx;
            unsigned long long old = atomicAdd(&packed[dst], inc);
            rank[e] = (unsigned short)(old >> 40);
        }
    } else if (b < nbE + 512) {
        int bb = b - nbE;
        const float* W = (bb < 256) ? W1 : W2;
        unsigned short* hi = (bb < 256) ? w1t_hi : w2t_hi;
        unsigned short* lo = (bb < 256) ? w1t_lo : w2t_lo;
        int n = bb & 255;      // col of W
        int k = threadIdx.x;   // row of W
        float v = W[(size_t)k * 256 + n];
        short2 s = split1(v);
        hi[(size_t)n * 256 + k] = (unsigned short)s.x;
        lo[(size_t)n * 256 + k] = (unsigned short)s.y;
    } else {
        int i = (b - nbE - 512) * 256 + threadIdx.x;   // 8-float group index
        if (i < nx8) {
            const float4* xp = (const float4*)x + 2 * (size_t)i;
            float4 v0 = xp[0], v1 = xp[1];
            u16x8 o;
            o[0] = f2bf(v0.x); o[1] = f2bf(v0.y); o[2] = f2bf(v0.z); o[3] = f2bf(v0.w);
            o[4] = f2bf(v1.x); o[5] = f2bf(v1.y); o[6] = f2bf(v1.z); o[7] = f2bf(v1.w);
            *(u16x8*)(x16 + (size_t)i * 8) = o;
        }
    }
}

// ---------------- exclusive scan of cnt -> row_ptr (3-kernel); scan1 also dinv ----------------
#define SCAN_B 256
__global__ void scan1_kernel(const unsigned long long* __restrict__ packed,
                             int* __restrict__ rp, int* __restrict__ bsum,
                             float* __restrict__ dinv, int N) {
    __shared__ int s[SCAN_B];
    int tid = threadIdx.x;
    int i = blockIdx.x * SCAN_B + tid;
    int v = 0;
    if (i < N) {
        unsigned long long pk = packed[i];
        v = (int)(pk >> 40);
        float deg = (float)(pk & DEG_MASK) * FIXED_INV;
        dinv[i] = rsqrtf(deg + 1.0f);         // +1 = self loop weight
    }
    s[tid] = v;
    __syncthreads();
    for (int off = 1; off < SCAN_B; off <<= 1) {
        int t = (tid >= off) ? s[tid - off] : 0;
        __syncthreads();
        s[tid] += t;
        __syncthreads();
    }
    if (i < N) rp[i] = s[tid] - v;            // exclusive within block
    if (tid == SCAN_B - 1) bsum[blockIdx.x] = s[tid];
}

__global__ void scan2_kernel(int* __restrict__ bsum, int* __restrict__ boff, int nb) {
    __shared__ int s[SCAN_B];
    int tid = threadIdx.x;
    int v = (tid < nb) ? bsum[tid] : 0;
    s[tid] = v;
    __syncthreads();
    for (int off = 1; off < SCAN_B; off <<= 1) {
        int t = (tid >= off) ? s[tid - off] : 0;
        __syncthreads();
        s[tid] += t;
        __syncthreads();
    }
    if (tid < nb) boff[tid] = s[tid] - v;     // exclusive across blocks
}

__global__ void scan3_kernel(int* __restrict__ rp, const int* __restrict__ boff,
                             int N, int E) {
    int i = blockIdx.x * blockDim.x + threadIdx.x;
    if (i < N) rp[i] = rp[i] + boff[i >> 8];
    if (i == 0) rp[N] = E;
}

// ---------------- CSR fill, ATOMIC-FREE: pos = rp[dst] + rank[e] ----------------
__global__ void fill_kernel(const int* __restrict__ ei, const float* __restrict__ w,
                            const float* __restrict__ dinv,
                            const int* __restrict__ rp,
                            const unsigned short* __restrict__ rank,
                            int2* __restrict__ cv, int E) {
    int e = blockIdx.x * blockDim.x + threadIdx.x;
    if (e >= E) return;
    int src = ei[e];
    int dst = ei[E + e];
    int pos = rp[dst] + (int)rank[e];
    // defensive clamp: never allow a wild store outside [0,E)
    if ((unsigned)pos < (unsigned)E) {
        float v = dinv[src] * w[e] * dinv[dst];
        cv[pos] = make_int2(src, __float_as_int(v));
    }
}

// ---------------- GEMM: C16 = A16 @ (Bh+Bl), plain-A 2-MFMA ----------------
// C16[N][256] plain bf16 out; A plain bf16 (its bf16 rounding == dropped al*bh
// term of the 3-MFMA split ladder — proven free in R17/R19); B hi/lo split.
__global__ __launch_bounds__(256) void gemm_kernel(
    const unsigned short* __restrict__ A16,
    const unsigned short* __restrict__ Bth,
    const unsigned short* __restrict__ Btl,
    unsigned short* __restrict__ C16, int Nrows)
{
    __shared__ __align__(16) short Ah[128 * 64];
    __shared__ __align__(16) short Bh[128 * 64];
    __shared__ __align__(16) short Bl[128 * 64];

    const int t    = threadIdx.x;
    const int lane = t & 63;
    const int w    = t >> 6;
    const int r0   = blockIdx.x * 128;
    const int cb0  = blockIdx.y * 128;
    const int fr   = lane & 15;          // frag row (A: m-row / B: n-col)
    const int fk   = (lane >> 4) * 8;    // frag k offset
    const int wm   = w * 32;             // wave's m-band

    f32x4 acc[2][8] = {};

    for (int k0 = 0; k0 < 256; k0 += 64) {
        __syncthreads();
        // ---- stage B tile [128 n][64 k] (hi+lo) ----
#pragma unroll
        for (int c = 0; c < 4; ++c) {
            int i = c * 256 + t;
            int row = i >> 3, seg = i & 7;
            size_t g = (size_t)(cb0 + row) * 256 + k0 + seg * 8;
            *(s16x8*)&Bh[row * 64 + seg * 8] = *(const s16x8*)(Bth + g);
            *(s16x8*)&Bl[row * 64 + seg * 8] = *(const s16x8*)(Btl + g);
        }
        // ---- stage A tile [128 m][64 k] ----
#pragma unroll
        for (int c = 0; c < 4; ++c) {
            int i = c * 256 + t;
            int row = i >> 3, seg = i & 7;
            int gr = r0 + row; if (gr > Nrows - 1) gr = Nrows - 1;
            size_t g = (size_t)gr * 256 + k0 + seg * 8;
            *(s16x8*)&Ah[row * 64 + seg * 8] = *(const s16x8*)(A16 + g);
        }
        __syncthreads();
        // ---- compute: 2 k-steps of 32, 2m x 8n frags, 2 MFMA each ----
#pragma unroll
        for (int ks = 0; ks < 2; ++ks) {
            int ko = ks * 32 + fk;
            bf16x8 ah[2];
#pragma unroll
            for (int mi = 0; mi < 2; ++mi)
                ah[mi] = *(const bf16x8*)&Ah[(wm + mi * 16 + fr) * 64 + ko];
#pragma unroll
            for (int n = 0; n < 8; ++n) {
                bf16x8 bh = *(const bf16x8*)&Bh[(n * 16 + fr) * 64 + ko];
                bf16x8 bl = *(const bf16x8*)&Bl[(n * 16 + fr) * 64 + ko];
#pragma unroll
                for (int mi = 0; mi < 2; ++mi) {
                    acc[mi][n] = __builtin_amdgcn_mfma_f32_16x16x32_bf16(ah[mi], bh, acc[mi][n], 0, 0, 0);
                    acc[mi][n] = __builtin_amdgcn_mfma_f32_16x16x32_bf16(ah[mi], bl, acc[mi][n], 0, 0, 0);
                }
            }
        }
    }
    // ---- epilogue: C/D layout col=lane&15, row=(lane>>4)*4+reg; store plain bf16 ----
    const int rb = (lane >> 4) * 4;
#pragma unroll
    for (int mi = 0; mi < 2; ++mi) {
#pragma unroll
        for (int n = 0; n < 8; ++n) {
            int col = cb0 + n * 16 + fr;
#pragma unroll
            for (int r = 0; r < 4; ++r) {
                int row = r0 + wm + mi * 16 + rb + r;
                if (row < Nrows) C16[(size_t)row * 256 + col] = f2bf(acc[mi][n][r]);
            }
        }
    }
}

// ---- 8-channel bf16 FMA helper ----
__device__ inline void fma8(float* acc, u16x8 g, float v) {
#pragma unroll
    for (int c = 0; c < 8; ++c) acc[c] = fmaf(v, bf2f(g[c]), acc[c]);
}

// ---------------- CSR aggregation + self loop + bias + relu (+optional fused head) ----
// R13-proven structure (112us, FETCH 361MB): bf16-h gather, HALF-WAVE-per-edge
// keeps the 16B/lane global_load_dwordx4 shape (8B loads collapse to ~2 in
// flight, 6.7x slower — R6/R7). One wave per dst; lane l handles 8 channels
// [8*(l&31),+8) of edge j+2t+(l>>5); 16-edge main loop = 8 dwordx4 in flight,
// 8-edge mid tier, then 2/1-edge tail. cv = packed (col,val).
// Channel-phasing REFUTED (R14/R15) — full-row gathers use every fetched byte.
// MODE 0: relu + plain bf16 out (half0 stores; lo-drop proven free in R17).
// MODE 1: relu + fused head (wave-reduce).
template<int MODE>
__global__ __launch_bounds__(256) void agg_kernel(const unsigned short* __restrict__ h16,
                                                  const int* __restrict__ rp,
                                                  const int2* __restrict__ cv,
                                                  const float* __restrict__ dinv,
                                                  const float* __restrict__ bias,
                                                  unsigned short* __restrict__ out_hi,
                                                  const float* __restrict__ Wf,
                                                  const float* __restrict__ bf,
                                                  float* __restrict__ out,
                                                  int N) {
    int d    = blockIdx.x * 4 + (threadIdx.x >> 6);
    int lane = threadIdx.x & 63;
    if (d >= N) return;
    int half = lane >> 5;
    int co   = (lane & 31) * 8;          // this lane's channel offset

    float di = dinv[d];
    float selfm = half ? 0.0f : di * di;           // count self loop once
    u16x8 sv = *(const u16x8*)(h16 + (size_t)d * 256 + co);
    float acc[8];
#pragma unroll
    for (int c = 0; c < 8; ++c) acc[c] = selfm * bf2f(sv[c]);

    int s = rp[d], e = rp[d + 1];
    int j = s;
    for (; j + 16 <= e; j += 16) {
        int   ec[8]; float ev[8];
#pragma unroll
        for (int t2 = 0; t2 < 8; ++t2) {
            int2 ca = cv[j + 2 * t2], cb = cv[j + 2 * t2 + 1];
            ec[t2] = half ? cb.x : ca.x;
            ev[t2] = __int_as_float(half ? cb.y : ca.y);
        }
        u16x8 g0 = *(const u16x8*)(h16 + (size_t)ec[0] * 256 + co);
        u16x8 g1 = *(const u16x8*)(h16 + (size_t)ec[1] * 256 + co);
        u16x8 g2 = *(const u16x8*)(h16 + (size_t)ec[2] * 256 + co);
        u16x8 g3 = *(const u16x8*)(h16 + (size_t)ec[3] * 256 + co);
        u16x8 g4 = *(const u16x8*)(h16 + (size_t)ec[4] * 256 + co);
        u16x8 g5 = *(const u16x8*)(h16 + (size_t)ec[5] * 256 + co);
        u16x8 g6 = *(const u16x8*)(h16 + (size_t)ec[6] * 256 + co);
        u16x8 g7 = *(const u16x8*)(h16 + (size_t)ec[7] * 256 + co);
        fma8(acc, g0, ev[0]);
        fma8(acc, g1, ev[1]);
        fma8(acc, g2, ev[2]);
        fma8(acc, g3, ev[3]);
        fma8(acc, g4, ev[4]);
        fma8(acc, g5, ev[5]);
        fma8(acc, g6, ev[6]);
        fma8(acc, g7, ev[7]);
    }
    for (; j + 8 <= e; j += 8) {
        int   ec[4]; float ev[4];
#pragma unroll
        for (int t2 = 0; t2 < 4; ++t2) {
            int2 ca = cv[j + 2 * t2], cb = cv[j + 2 * t2 + 1];
            ec[t2] = half ? cb.x : ca.x;
            ev[t2] = __int_as_float(half ? cb.y : ca.y);
        }
        u16x8 g0 = *(const u16x8*)(h16 + (size_t)ec[0] * 256 + co);
        u16x8 g1 = *(const u16x8*)(h16 + (size_t)ec[1] * 256 + co);
        u16x8 g2 = *(const u16x8*)(h16 + (size_t)ec[2] * 256 + co);
        u16x8 g3 = *(const u16x8*)(h16 + (size_t)ec[3] * 256 + co);
        fma8(acc, g0, ev[0]);
        fma8(acc, g1, ev[1]);
        fma8(acc, g2, ev[2]);
        fma8(acc, g3, ev[3]);
    }
    for (; j + 2 <= e; j += 2) {
        int2 ca = cv[j], cb = cv[j + 1];
        int   ee = half ? cb.x : ca.x;
        float vv = __int_as_float(half ? cb.y : ca.y);
        u16x8 g = *(const u16x8*)(h16 + (size_t)ee * 256 + co);
        fma8(acc, g, vv);
    }
    if (j < e) {                                    // single leftover edge
        int2 ca = cv[j];
        int   ee = ca.x;
        float vv = half ? 0.0f : __int_as_float(ca.y);
        u16x8 g = *(const u16x8*)(h16 + (size_t)ee * 256 + co);
        fma8(acc, g, vv);
    }

    // combine halves: both halves end with the full per-channel sums
#pragma unroll
    for (int c = 0; c < 8; ++c) acc[c] += __shfl_xor(acc[c], 32);

    float4 b0 = *(const float4*)(bias + co);
    float4 b1 = *(const float4*)(bias + co + 4);
    acc[0] = fmaxf(acc[0] + b0.x, 0.0f);
    acc[1] = fmaxf(acc[1] + b0.y, 0.0f);
    acc[2] = fmaxf(acc[2] + b0.z, 0.0f);
    acc[3] = fmaxf(acc[3] + b0.w, 0.0f);
    acc[4] = fmaxf(acc[4] + b1.x, 0.0f);
    acc[5] = fmaxf(acc[5] + b1.y, 0.0f);
    acc[6] = fmaxf(acc[6] + b1.z, 0.0f);
    acc[7] = fmaxf(acc[7] + b1.w, 0.0f);

    if constexpr (MODE == 0) {
        if (half == 0) {
            u16x8 hi;
#pragma unroll
            for (int c = 0; c < 8; ++c) hi[c] = f2bf(acc[c]);
            *(u16x8*)(out_hi + (size_t)d * 256 + co) = hi;
        }
    } else {
        float4 wf0 = *(const float4*)(Wf + co);
        float4 wf1 = *(const float4*)(Wf + co + 4);
        float sdot = acc[0] * wf0.x + acc[1] * wf0.y + acc[2] * wf0.z + acc[3] * wf0.w
                   + acc[4] * wf1.x + acc[5] * wf1.y + acc[6] * wf1.z + acc[7] * wf1.w;
        for (int o = 16; o; o >>= 1) sdot += __shfl_down(sdot, o);   // per-half reduce
        if (lane == 0) out[d] = sdot + bf[0];
    }
}

// ---------------- host launch ----------------
extern "C" void kernel_launch(void* const* d_in, const int* in_sizes, int n_in,
                              void* d_out, int out_size, void* d_ws, size_t ws_size,
                              hipStream_t stream) {
    const float* x  = (const float*)d_in[0];
    const int*   ei = (const int*)d_in[1];
    const float* w  = (const float*)d_in[2];
    const float* W1 = (const float*)d_in[3];
    const float* b1 = (const float*)d_in[4];
    const float* W2 = (const float*)d_in[5];
    const float* b2 = (const float*)d_in[6];
    const float* Wf = (const float*)d_in[7];
    const float* bf = (const float*)d_in[8];
    float* out = (float*)d_out;

    const int N = in_sizes[0] / IN_C;
    const int E = in_sizes[2];

    // workspace layout (256B aligned)
    auto align256 = [](size_t v) { return (v + 255) & ~(size_t)255; };
    char* p = (char*)d_ws;
    unsigned long long* packed = (unsigned long long*)p; p += align256((size_t)N * 8);
    float* dinv   = (float*)p; p += align256((size_t)N * 4);
    int*   rp     = (int*)p;   p += align256(((size_t)N + 1) * 4);
    int*   bsum   = (int*)p;   p += align256(SCAN_B * 4);
    int*   boff   = (int*)p;   p += align256(SCAN_B * 4);
    unsigned short* rank = (unsigned short*)p; p += align256((size_t)E * 2);
    int2*  cv     = (int2*)p;  p += align256((size_t)E * 8);
    unsigned short* w1t_hi = (unsigned short*)p; p += align256((size_t)256 * 256 * 2);
    unsigned short* w1t_lo = (unsigned short*)p; p += align256((size_t)256 * 256 * 2);
    unsigned short* w2t_hi = (unsigned short*)p; p += align256((size_t)256 * 256 * 2);
    unsigned short* w2t_lo = (unsigned short*)p; p += align256((size_t)256 * 256 * 2);
    unsigned short* hbuf  = (unsigned short*)p; p += align256((size_t)N * 256 * 2);  // bf16 GEMM out
    // xa16: x plain bf16 (read by GEMM1), then REUSED as a1 (plain bf16) by agg1
    unsigned short* xa16 = (unsigned short*)p; p += align256((size_t)N * 256 * 2);
    (void)ws_size; (void)n_in; (void)out_size;

    const int nbE      = (E + 255) / 256;
    const int nb_nodes = (N + 255) / 256;
    const int nb_scan  = (N + SCAN_B - 1) / SCAN_B;
    const int nx8      = N * 256 / 8;
    const int nb_x     = (nx8 + 255) / 256;

    // zero packed deg/cnt accumulators
    hipMemsetAsync(packed, 0, (size_t)N * 8, stream);

    // build1: deg_count || W prep || x convert (all low-resource branches)
    build1_kernel<<<nbE + 512 + nb_x, 256, 0, stream>>>(
        ei, w, packed, rank, E, nbE,
        W1, W2, w1t_hi, w1t_lo, w2t_hi, w2t_lo, x, xa16, nx8);

    // scan chain
    scan1_kernel<<<nb_scan, SCAN_B, 0, stream>>>(packed, rp, bsum, dinv, N);
    scan2_kernel<<<1, SCAN_B, 0, stream>>>(bsum, boff, nb_scan);
    scan3_kernel<<<nb_nodes, 256, 0, stream>>>(rp, boff, N, E);

    // CSR fill (atomic-free, high occupancy — kept separate from GEMM)
    fill_kernel<<<nbE, 256, 0, stream>>>(ei, w, dinv, rp, rank, cv, E);

    const int nb_agg = (N + 3) / 4;
    dim3 ggrid((N + 127) / 128, 2);

    // layer 1: GEMM (plain bf16 x) -> bf16 h -> agg1 (plain bf16 a1 into xa16)
    gemm_kernel<<<ggrid, 256, 0, stream>>>(xa16, w1t_hi, w1t_lo, hbuf, N);
    agg_kernel<0><<<nb_agg, 256, 0, stream>>>(hbuf, rp, cv, dinv, b1,
                                              xa16, nullptr, nullptr, nullptr, N);
    // layer 2: GEMM (plain bf16 a1) -> bf16 h -> agg2 + fused head
    gemm_kernel<<<ggrid, 256, 0, stream>>>(xa16, w2t_hi, w2t_lo, hbuf, N);
    agg_kernel<1><<<nb_agg, 256, 0, stream>>>(hbuf, rp, cv, dinv, b2,
                                              nullptr, Wf, bf, out, N);
}